// Round 1
// baseline (81.998 us; speedup 1.0000x reference)
//
#include <hip/hip_runtime.h>
#include <stdint.h>

// 24x24-bit binary multiplier on float bit-vectors.
// A,B: [BATCH,24] LSB-first {0.0,1.0}; out: [BATCH,48] LSB-first bits of a*b.
// The reference's partial-product + ripple-carry tree is exactly integer
// multiplication mod 2^48 (no overflow for 24x24), so: pack -> imul -> unpack.

#define NBATCH 131072
#define N_BITS 24
#define OUT_BITS 48

__global__ __launch_bounds__(256) void ArrayMultiplier24x24_kernel(
    const float* __restrict__ A,
    const float* __restrict__ B,
    float* __restrict__ out)
{
    int i = blockIdx.x * blockDim.x + threadIdx.x;
    if (i >= NBATCH) return;

    // Rows are 96B (in) / 192B (out), both 16B-aligned -> float4 ok.
    const float4* a4 = reinterpret_cast<const float4*>(A + (size_t)i * N_BITS);
    const float4* b4 = reinterpret_cast<const float4*>(B + (size_t)i * N_BITS);

    uint32_t a = 0u, b = 0u;
#pragma unroll
    for (int q = 0; q < 6; ++q) {
        float4 va = a4[q];
        float4 vb = b4[q];
        int s = 4 * q;
        // values are exactly 0.0f or 1.0f
        a |= ((uint32_t)va.x) << (s + 0);
        a |= ((uint32_t)va.y) << (s + 1);
        a |= ((uint32_t)va.z) << (s + 2);
        a |= ((uint32_t)va.w) << (s + 3);
        b |= ((uint32_t)vb.x) << (s + 0);
        b |= ((uint32_t)vb.y) << (s + 1);
        b |= ((uint32_t)vb.z) << (s + 2);
        b |= ((uint32_t)vb.w) << (s + 3);
    }

    uint64_t p = (uint64_t)a * (uint64_t)b;

    float4* o4 = reinterpret_cast<float4*>(out + (size_t)i * OUT_BITS);
#pragma unroll
    for (int q = 0; q < 12; ++q) {
        int s = 4 * q;
        float4 v;
        v.x = (float)((uint32_t)(p >> (s + 0)) & 1u);
        v.y = (float)((uint32_t)(p >> (s + 1)) & 1u);
        v.z = (float)((uint32_t)(p >> (s + 2)) & 1u);
        v.w = (float)((uint32_t)(p >> (s + 3)) & 1u);
        o4[q] = v;
    }
}

extern "C" void kernel_launch(void* const* d_in, const int* in_sizes, int n_in,
                              void* d_out, int out_size, void* d_ws, size_t ws_size,
                              hipStream_t stream)
{
    const float* A = (const float*)d_in[0];
    const float* B = (const float*)d_in[1];
    float* out = (float*)d_out;

    const int threads = 256;
    const int blocks = (NBATCH + threads - 1) / threads;  // 512
    ArrayMultiplier24x24_kernel<<<blocks, threads, 0, stream>>>(A, B, out);
}

// Round 2
// 76.658 us; speedup vs baseline: 1.0697x; 1.0697x over previous
//
#include <hip/hip_runtime.h>
#include <stdint.h>

// 24x24-bit binary multiplier on float bit-vectors.
// A,B: [131072,24] LSB-first {0.0,1.0}; out: [131072,48] LSB-first bits of a*b.
// Reference's partial-product + ripple-carry tree == integer multiply (no
// overflow at 24x24 -> 48 bits): pack bits -> u64 imul -> unpack bits.
//
// This version makes ALL global accesses lane-contiguous (round-1 version used
// 96B/192B-strided float4 accesses -> ~64 L2 transactions per wave instr).
// Inputs are loaded in flat coalesced order, packed to nibbles via an LDS
// redistribution table; outputs are produced in flat coalesced order with the
// (cheap) 64-bit product recomputed per output fragment via LDS broadcast.

#define NBATCH 131072
#define RPB    256           // rows per block
#define NF4IN  (RPB * 6)     // 1536 input float4s per operand per block

__global__ __launch_bounds__(256) void ArrayMultiplier24x24_kernel(
    const uint4* __restrict__ A4,   // [NBATCH*6] bit-pattern view of floats
    const uint4* __restrict__ B4,
    float4* __restrict__ O4)        // [NBATCH*12]
{
    __shared__ uint32_t nibA[NF4IN];   // 6 KB
    __shared__ uint32_t nibB[NF4IN];   // 6 KB
    __shared__ uint32_t packA[RPB];    // 1 KB
    __shared__ uint32_t packB[RPB];    // 1 KB

    const int t = threadIdx.x;
    const size_t inBase  = (size_t)blockIdx.x * NF4IN;     // f4 index
    const size_t outBase = (size_t)blockIdx.x * (RPB * 12);

    // Phase 1: coalesced loads (lane-contiguous f4 index), pack 4 bits/f4.
    // float 1.0f = 0x3F800000 -> bit = (u >> 29) & 1.
#pragma unroll
    for (int k = 0; k < 6; ++k) {
        int f = k * 256 + t;                 // 0..1535, bijective
        uint4 va = A4[inBase + f];
        uint4 vb = B4[inBase + f];
        uint32_t na = ((va.x >> 29) & 1u) | ((va.y >> 28) & 2u) |
                      ((va.z >> 27) & 4u) | ((va.w >> 26) & 8u);
        uint32_t nb = ((vb.x >> 29) & 1u) | ((vb.y >> 28) & 2u) |
                      ((vb.z >> 27) & 4u) | ((vb.w >> 26) & 8u);
        nibA[f] = na;                        // bank = f%32: conflict-free
        nibB[f] = nb;
    }
    __syncthreads();

    // Phase 2: gather own row's 6 nibbles -> 24-bit operands.
    // f4 index f = row*6 + seg (row-major), so row t's nibbles are t*6+s.
    uint32_t a = 0u, b = 0u;
#pragma unroll
    for (int s = 0; s < 6; ++s) {
        a |= nibA[t * 6 + s] << (4 * s);     // ~4-way bank conflict, tiny
        b |= nibB[t * 6 + s] << (4 * s);
    }
    packA[t] = a;
    packB[t] = b;
    __syncthreads();

    // Phase 3: produce output float4s in flat coalesced order.
    // Output f4 g (0..3071) = row g/12, bit offset (g%12)*4.
#pragma unroll
    for (int k = 0; k < 12; ++k) {
        int g = k * 256 + t;
        int row = g / 12;                    // u24 magic-mul, cheap
        int c0 = (g - row * 12) * 4;
        uint64_t p = (uint64_t)packA[row] * (uint64_t)packB[row]; // broadcast reads
        float4 v;
        v.x = (float)((uint32_t)(p >> (c0 + 0)) & 1u);
        v.y = (float)((uint32_t)(p >> (c0 + 1)) & 1u);
        v.z = (float)((uint32_t)(p >> (c0 + 2)) & 1u);
        v.w = (float)((uint32_t)(p >> (c0 + 3)) & 1u);
        O4[outBase + g] = v;                 // lane-contiguous store
    }
}

extern "C" void kernel_launch(void* const* d_in, const int* in_sizes, int n_in,
                              void* d_out, int out_size, void* d_ws, size_t ws_size,
                              hipStream_t stream)
{
    const uint4* A4 = (const uint4*)d_in[0];
    const uint4* B4 = (const uint4*)d_in[1];
    float4* O4 = (float4*)d_out;

    const int blocks = NBATCH / RPB;   // 512
    ArrayMultiplier24x24_kernel<<<blocks, 256, 0, stream>>>(A4, B4, O4);
}

// Round 3
// 75.617 us; speedup vs baseline: 1.0844x; 1.0138x over previous
//
#include <hip/hip_runtime.h>
#include <stdint.h>

// 24x24-bit binary multiplier on float bit-vectors.
// A,B: [131072,24] LSB-first {0.0,1.0}; out: [131072,48] LSB-first bits of a*b.
// Reference's partial-product + ripple-carry tree == integer multiply (no
// overflow at 24x24 -> 48 bits): pack bits -> u64 imul -> unpack bits.
//
// R3: wave-autonomous version. R2 (LDS + 2 barriers, 512 blocks = 8 waves/CU)
// was latency-bound, ~2.3 TB/s. Here each wave owns 32 rows:
//   input  A,B: 32 rows * 6 f4 = 192 f4 = 3 lane-contiguous uint4 loads/wave
//   output    : 32 rows * 12 f4 = 384 f4 = 6 lane-contiguous float4 stores/wave
// Cross-lane bit redistribution via __shfl (ds_bpermute) -- no LDS, no
// __syncthreads, 4096 waves (1024 blocks x 256) = 16 waves/CU.

#define NBATCH 131072
#define ROWS_PER_WAVE 32
#define N_WAVES (NBATCH / ROWS_PER_WAVE)     // 4096
#define WAVES_PER_BLOCK 4
#define N_BLOCKS (N_WAVES / WAVES_PER_BLOCK) // 1024

__global__ __launch_bounds__(256) void ArrayMultiplier24x24_kernel(
    const uint4* __restrict__ A4,   // bit-pattern view of floats, 6 f4/row
    const uint4* __restrict__ B4,
    float4* __restrict__ O4)        // 12 f4/row
{
    const int l = threadIdx.x & 63;
    const int w = blockIdx.x * WAVES_PER_BLOCK + (threadIdx.x >> 6);
    const size_t inBase  = (size_t)w * (ROWS_PER_WAVE * 6);   // 192 f4
    const size_t outBase = (size_t)w * (ROWS_PER_WAVE * 12);  // 384 f4

    // Phase 1: lane-contiguous loads; pack each f4 (4 floats in {0,1}) to a
    // nibble. 1.0f = 0x3F800000 -> bit = (u >> 29) & 1.
    uint32_t nA[3], nB[3];
#pragma unroll
    for (int k = 0; k < 3; ++k) {
        uint4 va = A4[inBase + k * 64 + l];
        uint4 vb = B4[inBase + k * 64 + l];
        nA[k] = ((va.x >> 29) & 1u) | ((va.y >> 28) & 2u) |
                ((va.z >> 27) & 4u) | ((va.w >> 26) & 8u);
        nB[k] = ((vb.x >> 29) & 1u) | ((vb.y >> 28) & 2u) |
                ((vb.z >> 27) & 4u) | ((vb.w >> 26) & 8u);
    }

    // Phase 2: gather row r's 6 nibbles via shuffles. Row r's s-th nibble
    // lives at flat f4 index r*6+s = reg (idx>>6), lane (idx&63).
    // Lanes 32..63 duplicate rows 0..31 (harmless; shfl sources lanes 0..31).
    const int r = l & 31;
    uint32_t a = 0u, b = 0u;
#pragma unroll
    for (int s = 0; s < 6; ++s) {
        int idx = r * 6 + s;
        int src = idx & 63;
        int k   = idx >> 6;            // 0..2
        uint32_t a0 = __shfl(nA[0], src, 64);
        uint32_t a1 = __shfl(nA[1], src, 64);
        uint32_t a2 = __shfl(nA[2], src, 64);
        uint32_t b0 = __shfl(nB[0], src, 64);
        uint32_t b1 = __shfl(nB[1], src, 64);
        uint32_t b2 = __shfl(nB[2], src, 64);
        uint32_t av = (k == 0) ? a0 : ((k == 1) ? a1 : a2);
        uint32_t bv = (k == 0) ? b0 : ((k == 1) ? b1 : b2);
        a |= av << (4 * s);
        b |= bv << (4 * s);
    }

    // The multiply (lane r holds row r's product).
    uint64_t p = (uint64_t)a * (uint64_t)b;
    uint32_t plo = (uint32_t)p, phi = (uint32_t)(p >> 32);

    // Phase 3: lane-contiguous stores. Output f4 g (0..383) = row g/12,
    // bits (g%12)*4 .. +3 of that row's product (fetched from lane g/12).
#pragma unroll
    for (int k = 0; k < 6; ++k) {
        int g = k * 64 + l;
        int row = g / 12;                  // 0..31 (magic-mul)
        int c0 = (g - row * 12) * 4;       // 0..44
        uint32_t lo = __shfl(plo, row, 64);
        uint32_t hi = __shfl(phi, row, 64);
        uint64_t pp = ((uint64_t)hi << 32) | lo;
        uint32_t bits = (uint32_t)(pp >> c0);
        float4 v;
        v.x = (float)(bits & 1u);
        v.y = (float)((bits >> 1) & 1u);
        v.z = (float)((bits >> 2) & 1u);
        v.w = (float)((bits >> 3) & 1u);
        O4[outBase + g] = v;
    }
}

extern "C" void kernel_launch(void* const* d_in, const int* in_sizes, int n_in,
                              void* d_out, int out_size, void* d_ws, size_t ws_size,
                              hipStream_t stream)
{
    const uint4* A4 = (const uint4*)d_in[0];
    const uint4* B4 = (const uint4*)d_in[1];
    float4* O4 = (float4*)d_out;

    ArrayMultiplier24x24_kernel<<<N_BLOCKS, 256, 0, stream>>>(A4, B4, O4);
}